// Round 1
// baseline (445.849 us; speedup 1.0000x reference)
//
#include <hip/hip_runtime.h>
#include <math.h>

// Problem constants (fixed by the reference)
constexpr int Bc = 4096;
constexpr int Tc = 200;
constexpr int Cc = 38;   // classes (0 = blank)
constexpr int Sc = 30;   // max target length
constexpr int Lc = 2 * Sc + 1;  // 61 lattice states
#define NEGV (-1e9f)

__device__ __forceinline__ float lae(float a, float b) {
    // jnp.logaddexp semantics with finite inputs
    float mx = fmaxf(a, b);
    float mn = fminf(a, b);
    return mx + log1pf(__expf(mn - mx));
}

// One wave (64 lanes) per sample. Lane l = lattice state l (l < 61).
__global__ __launch_bounds__(256) void ctc_kl_kernel(
    const float* __restrict__ input,   // [B,T,C]
    const int*   __restrict__ target,  // [B,S]
    const int*   __restrict__ ilen,    // [B]
    const int*   __restrict__ tlen,    // [B]
    const int*   __restrict__ pos,     // [B,S]
    const float* __restrict__ ms,      // [37,37,37] row-stochastic
    float*       __restrict__ contrib) // [B] per-sample loss contribution
{
    const int lane = threadIdx.x & 63;
    const int wave = threadIdx.x >> 6;
    const int b = blockIdx.x * 4 + wave;
    if (b >= Bc) return;

    // --- lattice static data (per lane) ---
    int ext = 0;       // class for this lattice state
    bool skip = false; // allow_skip for this state
    if (lane < Lc && (lane & 1)) {
        int s = (lane - 1) >> 1;
        ext = target[b * Sc + s];                       // 1..37
        int prev = (s > 0) ? target[b * Sc + s - 1] : 0;
        skip = (ext != prev);                           // ext != 0 always
    }

    float alpha = (lane == 0) ? 0.0f : NEGV;
    const float* row = input + (size_t)b * Tc * Cc;
    const int il = ilen[b];

    // --- CTC forward recursion ---
    for (int t = 0; t < Tc; ++t) {
        float x = (lane < Cc) ? row[t * Cc + lane] : -1e30f;
        // wave-wide logsumexp over classes
        float m = x;
        #pragma unroll
        for (int o = 32; o; o >>= 1) m = fmaxf(m, __shfl_xor(m, o));
        float e = (lane < Cc) ? __expf(x - m) : 0.0f;
        #pragma unroll
        for (int o = 32; o; o >>= 1) e += __shfl_xor(e, o);
        float lse = m + __logf(e);
        float emit = __shfl(x, ext) - lse;  // log_prob of this state's class

        float a1 = __shfl_up(alpha, 1);
        if (lane < 1) a1 = NEGV;
        float a2 = __shfl_up(alpha, 2);
        if (lane < 2 || !skip) a2 = NEGV;

        float na = lae(lae(alpha, a1), a2) + emit;
        if (t < il) alpha = na;
    }

    const int tl = tlen[b];
    const int idx = 2 * tl;                 // 10..60
    float last  = __shfl(alpha, idx);
    float last2 = __shfl(alpha, idx - 1);
    float nll = -lae(last, last2);
    if (nll > 1e8f) nll = 0.0f;             // zero_infinity
    float ctc_part = (nll / (float)tl) / (float)Bc;  // contribution to mean

    // --- aligned-KL smoothing branch ---
    float acc = 0.0f;  // sum_s w * kl_row  (valid s only)
    for (int s = 0; s < tl; ++s) {
        int p = pos[b * Sc + s];            // emission time
        float x = (lane < Cc) ? row[p * Cc + lane] : -1e30f;
        float m = x;
        #pragma unroll
        for (int o = 32; o; o >>= 1) m = fmaxf(m, __shfl_xor(m, o));
        float e = (lane < Cc) ? __expf(x - m) : 0.0f;
        #pragma unroll
        for (int o = 32; o; o >>= 1) e += __shfl_xor(e, o);
        float lse = m + __logf(e);

        int tg = target[b * Sc + s];                    // 1..37
        int f  = (s > 0) ? target[b * Sc + s - 1] : Cc - 1; // 37 for s==0
        float sls = 0.0f;
        if (lane >= 1 && lane < Cc)
            sls = ms[((size_t)(f - 1) * 37 + (tg - 1)) * 37 + (lane - 1)];
        float tv   = sls + 1e-10f;
        float pred = x - lse;                            // log_prob at pos
        float term = (lane < Cc) ? tv * (logf(tv) - pred) : 0.0f;
        float wv   = (lane < Cc) ? sls : 0.0f;
        #pragma unroll
        for (int o = 32; o; o >>= 1) {
            term += __shfl_xor(term, o);
            wv   += __shfl_xor(wv, o);
        }
        acc += wv * (term / (float)Cc);
    }
    float Lf = (float)tl;
    float per_sample = acc / Lf;
    float smoothing = 1.0f - powf(1.0f - 0.05f, 1.0f / Lf);
    float kld = smoothing * per_sample;

    if (lane == 0) contrib[b] = ctc_part + kld;
}

// Deterministic single-block tree reduction of B floats -> out[0]
__global__ __launch_bounds__(256) void reduce_kernel(
    const float* __restrict__ in, float* __restrict__ out, int n)
{
    __shared__ float sdata[256];
    float s = 0.0f;
    for (int i = threadIdx.x; i < n; i += 256) s += in[i];
    sdata[threadIdx.x] = s;
    __syncthreads();
    for (int off = 128; off; off >>= 1) {
        if ((int)threadIdx.x < off) sdata[threadIdx.x] += sdata[threadIdx.x + off];
        __syncthreads();
    }
    if (threadIdx.x == 0) out[0] = sdata[0];
}

extern "C" void kernel_launch(void* const* d_in, const int* in_sizes, int n_in,
                              void* d_out, int out_size, void* d_ws, size_t ws_size,
                              hipStream_t stream) {
    const float* input  = (const float*)d_in[0];
    const int*   target = (const int*)d_in[1];
    const int*   ilen   = (const int*)d_in[2];
    const int*   tlen   = (const int*)d_in[3];
    const int*   pos    = (const int*)d_in[4];
    const float* ms     = (const float*)d_in[5];
    float* out = (float*)d_out;
    float* contrib = (float*)d_ws;  // B floats

    ctc_kl_kernel<<<Bc / 4, 256, 0, stream>>>(input, target, ilen, tlen, pos, ms, contrib);
    reduce_kernel<<<1, 256, 0, stream>>>(contrib, out, Bc);
}

// Round 2
// 116.328 us; speedup vs baseline: 3.8327x; 3.8327x over previous
//
#include <hip/hip_runtime.h>
#include <math.h>

// Problem constants (fixed by the reference)
constexpr int Bc = 4096;
constexpr int Tc = 200;
constexpr int Cc = 38;   // classes (0 = blank)
constexpr int Sc = 30;   // max target length
constexpr int Lc = 2 * Sc + 1;  // 61 lattice states
#define NEGV (-1e9f)

// DPP wave_shr:1 — lane i gets v from lane i-1, lane 0 gets `fill`.
// VALU-only (no DS), bound_ctrl=false keeps `old` (=fill) for invalid lane 0.
__device__ __forceinline__ float dpp_shr1(float v, float fill) {
    int r = __builtin_amdgcn_update_dpp(__float_as_int(fill), __float_as_int(v),
                                        0x138, 0xF, 0xF, false);
    return __int_as_float(r);
}

// ---------- Pass 1: per-row logsumexp over classes (fully parallel) ----------
__global__ __launch_bounds__(256) void lse_kernel(
    const float* __restrict__ input,  // [B,T,C]
    float*       __restrict__ lse)    // [B*T]
{
    int r = blockIdx.x * 256 + threadIdx.x;
    if (r >= Bc * Tc) return;
    const float2* p = (const float2*)(input + (size_t)r * Cc);  // 152B row, 8B-aligned
    float x[Cc];
    #pragma unroll
    for (int i = 0; i < Cc / 2; ++i) {
        float2 v = p[i];
        x[2 * i] = v.x; x[2 * i + 1] = v.y;
    }
    float m = x[0];
    #pragma unroll
    for (int i = 1; i < Cc; ++i) m = fmaxf(m, x[i]);
    float s = 0.0f;
    #pragma unroll
    for (int i = 0; i < Cc; ++i) s += __expf(x[i] - m);
    lse[r] = m + __logf(s);
}

// ---------- Pass 2: CTC recursion (shifted space) + aligned-KL ----------
// One wave per sample; lane l = lattice state l.
__global__ __launch_bounds__(256) void ctc_kl_kernel(
    const float* __restrict__ input,    // [B,T,C]
    const int*   __restrict__ target,   // [B,S]
    const int*   __restrict__ ilen,     // [B]
    const int*   __restrict__ tlen,     // [B]
    const int*   __restrict__ pos,      // [B,S]
    const float* __restrict__ ms,       // [37,37,37]
    const float* __restrict__ lse_arr,  // [B*T]
    float*       __restrict__ contrib)  // [B]
{
    const int lane = threadIdx.x & 63;
    const int wave = threadIdx.x >> 6;
    const int b = blockIdx.x * 4 + wave;
    if (b >= Bc) return;

    // static lattice data
    int ext = 0;       // class of this lattice state (blank=0 for even/out-of-range lanes)
    bool skip = false; // allow_skip
    if (lane < Lc && (lane & 1)) {
        int s = (lane - 1) >> 1;
        ext = target[b * Sc + s];                        // 1..37
        int prev = (s > 0) ? target[b * Sc + s - 1] : 0;
        skip = (ext != prev);
    }

    const float* row = input + (size_t)b * Tc * Cc;
    const float* ep  = row + ext;         // per-lane gather base
    const int il = ilen[b];
    const int tl = tlen[b];

    // beta = alpha + cumsum(lse): the common lse shift cancels inside logsumexp3,
    // so the serial loop needs no lse. Subtract sum(lse[t<il]) at the end.
    float beta = (lane == 0) ? 0.0f : NEGV;
    #pragma unroll 4
    for (int t = 0; t < il; ++t) {
        float e  = ep[t * Cc];            // x[t, ext_l] (per-lane gather, L1-resident)
        float b1 = dpp_shr1(beta, NEGV);
        float b2 = dpp_shr1(b1, NEGV);
        b2 = skip ? b2 : NEGV;
        float m3 = fmaxf(fmaxf(beta, b1), b2);          // v_max3
        float s3 = __expf(beta - m3) + __expf(b1 - m3) + __expf(b2 - m3);
        beta = m3 + __logf(s3) + e;
    }

    // sum of lse over t < il (wave-parallel)
    const float* lrow = lse_arr + (size_t)b * Tc;
    float cl = 0.0f;
    for (int i = lane; i < il; i += 64) cl += lrow[i];
    #pragma unroll
    for (int o = 32; o; o >>= 1) cl += __shfl_xor(cl, o);

    const int idx = 2 * tl;               // 10..60
    float last  = __shfl(beta, idx);
    float last2 = __shfl(beta, idx - 1);
    float mx = fmaxf(last, last2);
    float l2 = mx + __logf(__expf(last - mx) + __expf(last2 - mx));
    float nll = cl - l2;                  // -(logaddexp(alpha_idx, alpha_idx-1))
    if (nll > 1e8f) nll = 0.0f;           // zero_infinity
    float ctc_part = nll / ((float)tl * (float)Bc);

    // ---- aligned-KL smoothing (lse precomputed; w = sum(SLS) == 1.0 row-stochastic) ----
    float acc = 0.0f;
    for (int s = 0; s < tl; ++s) {
        int p  = pos[b * Sc + s];
        int tg = target[b * Sc + s];
        int f  = (s > 0) ? target[b * Sc + s - 1] : Cc - 1;
        float lsp = lrow[p];
        float x = (lane < Cc) ? row[p * Cc + lane] : 0.0f;
        float sls = 0.0f;
        if (lane >= 1 && lane < Cc)
            sls = ms[((size_t)(f - 1) * 37 + (tg - 1)) * 37 + (lane - 1)];
        float tv = sls + 1e-10f;
        float term = (lane < Cc) ? tv * (__logf(tv) - (x - lsp)) : 0.0f;
        #pragma unroll
        for (int o = 32; o; o >>= 1) term += __shfl_xor(term, o);
        acc += term * (1.0f / (float)Cc); // kl_row mean over C; w==1
    }
    float Lf = (float)tl;
    float per_sample = acc / Lf;
    float smoothing = 1.0f - __expf(-0.05129329439f / Lf);  // 1 - 0.95^(1/Lf)
    float kld = smoothing * per_sample;

    if (lane == 0) contrib[b] = ctc_part + kld;
}

// Deterministic single-block tree reduction of B floats -> out[0]
__global__ __launch_bounds__(256) void reduce_kernel(
    const float* __restrict__ in, float* __restrict__ out, int n)
{
    __shared__ float sdata[256];
    float s = 0.0f;
    for (int i = threadIdx.x; i < n; i += 256) s += in[i];
    sdata[threadIdx.x] = s;
    __syncthreads();
    for (int off = 128; off; off >>= 1) {
        if ((int)threadIdx.x < off) sdata[threadIdx.x] += sdata[threadIdx.x + off];
        __syncthreads();
    }
    if (threadIdx.x == 0) out[0] = sdata[0];
}

extern "C" void kernel_launch(void* const* d_in, const int* in_sizes, int n_in,
                              void* d_out, int out_size, void* d_ws, size_t ws_size,
                              hipStream_t stream) {
    const float* input  = (const float*)d_in[0];
    const int*   target = (const int*)d_in[1];
    const int*   ilen   = (const int*)d_in[2];
    const int*   tlen   = (const int*)d_in[3];
    const int*   pos    = (const int*)d_in[4];
    const float* ms     = (const float*)d_in[5];
    float* out = (float*)d_out;

    // ws layout: contrib [Bc] | lse [Bc*Tc]  (~3.3 MB)
    float* contrib = (float*)d_ws;
    float* lse     = contrib + Bc;

    lse_kernel<<<(Bc * Tc + 255) / 256, 256, 0, stream>>>(input, lse);
    ctc_kl_kernel<<<Bc / 4, 256, 0, stream>>>(input, target, ilen, tlen, pos, ms, lse, contrib);
    reduce_kernel<<<1, 256, 0, stream>>>(contrib, out, Bc);
}

// Round 3
// 88.909 us; speedup vs baseline: 5.0147x; 1.3084x over previous
//
#include <hip/hip_runtime.h>
#include <math.h>

// Problem constants (fixed by the reference)
constexpr int Bc = 4096;
constexpr int Tc = 200;
constexpr int Cc = 38;   // classes (0 = blank)
constexpr int Sc = 30;   // max target length
constexpr int Lc = 2 * Sc + 1;  // 61 lattice states
#define NEGV (-1e9f)
#define LOG2E 1.4426950408889634f
#define LN2   0.6931471805599453f

// DPP wave_shr:1 — lane i gets v from lane i-1, lane 0 keeps `fill`.
__device__ __forceinline__ float dpp_shr1(float v, float fill) {
    int r = __builtin_amdgcn_update_dpp(__float_as_int(fill), __float_as_int(v),
                                        0x138, 0xF, 0xF, false);
    return __int_as_float(r);
}

// ---------- Pass 1: per-row logsumexp over classes (fully parallel) ----------
__global__ __launch_bounds__(256) void lse_kernel(
    const float* __restrict__ input,  // [B,T,C]
    float*       __restrict__ lse)    // [B*T]
{
    int r = blockIdx.x * 256 + threadIdx.x;
    if (r >= Bc * Tc) return;
    const float2* p = (const float2*)(input + (size_t)r * Cc);
    float x[Cc];
    #pragma unroll
    for (int i = 0; i < Cc / 2; ++i) {
        float2 v = p[i];
        x[2 * i] = v.x; x[2 * i + 1] = v.y;
    }
    float m = x[0];
    #pragma unroll
    for (int i = 1; i < Cc; ++i) m = fmaxf(m, x[i]);
    float s = 0.0f;
    #pragma unroll
    for (int i = 0; i < Cc; ++i) s += __expf(x[i] - m);
    lse[r] = m + __logf(s);
}

// ---------- Pass 2: aligned-KL smoothing, one thread per (b,s) ----------
__global__ __launch_bounds__(256) void kl_kernel(
    const float* __restrict__ input,   // [B,T,C]
    const int*   __restrict__ target,  // [B,S]
    const int*   __restrict__ tlen,    // [B]
    const int*   __restrict__ pos,     // [B,S]
    const float* __restrict__ ms,      // [37,37,37]
    const float* __restrict__ lse_arr, // [B*T]
    float*       __restrict__ klws)    // [B*S] scaled per-(b,s) KL terms
{
    int idx = blockIdx.x * 256 + threadIdx.x;
    if (idx >= Bc * Sc) return;
    int b = idx / Sc;
    int s = idx - b * Sc;
    int tl = tlen[b];
    float outv = 0.0f;
    if (s < tl) {
        int p  = pos[b * Sc + s];
        int tg = target[b * Sc + s];
        int f  = (s > 0) ? target[b * Sc + s - 1] : Cc - 1;
        float lsp = lse_arr[(size_t)b * Tc + p];
        const float* xr  = input + ((size_t)b * Tc + p) * Cc;
        const float* msr = ms + ((size_t)(f - 1) * 37 + (tg - 1)) * 37;
        // c = 0 (blank): sls = 0
        float acc = 1e-10f * (__logf(1e-10f) - (xr[0] - lsp));
        #pragma unroll
        for (int c = 1; c < Cc; ++c) {
            float tv = msr[c - 1] + 1e-10f;
            acc += tv * (__logf(tv) - (xr[c] - lsp));
        }
        float Lf = (float)tl;
        float smoothing = 1.0f - __expf(-0.05129329438755058f / Lf); // 1-0.95^(1/Lf)
        outv = acc * smoothing / ((float)Cc * Lf);
    }
    klws[idx] = outv;
}

// ---------- Pass 3: CTC recursion (log2 shifted space, deep prefetch) ----------
// One wave per sample; lane l = lattice state l.
__global__ __launch_bounds__(256) void ctc_kernel(
    const float* __restrict__ input,    // [B,T,C]
    const int*   __restrict__ target,   // [B,S]
    const int*   __restrict__ ilen,     // [B]
    const int*   __restrict__ tlen,     // [B]
    const float* __restrict__ lse_arr,  // [B*T]
    const float* __restrict__ klws,     // [B*S]
    float*       __restrict__ contrib)  // [B]
{
    const int lane = threadIdx.x & 63;
    const int wave = threadIdx.x >> 6;
    const int b = blockIdx.x * 4 + wave;
    if (b >= Bc) return;

    int ext = 0;
    bool skip = false;
    if (lane < Lc && (lane & 1)) {
        int s = (lane - 1) >> 1;
        ext = target[b * Sc + s];
        int prev = (s > 0) ? target[b * Sc + s - 1] : 0;
        skip = (ext != prev);
    }

    const float* row = input + (size_t)b * Tc * Cc;
    const float* ep  = row + ext;
    const int il = ilen[b];
    const int tl = tlen[b];

    // Rolling register prefetch: PF rows ahead (statically indexed).
    constexpr int PF = 16;
    float pre[PF];
    #pragma unroll
    for (int k = 0; k < PF; ++k) pre[k] = ep[k * Cc];   // k < Tc always

    // beta in LOG2 units; common lse shift cancels (subtracted at the end).
    float beta = (lane == 0) ? 0.0f : NEGV;
    int t = 0;
    for (; t + PF <= il; t += PF) {
        #pragma unroll
        for (int k = 0; k < PF; ++k) {
            float e2 = pre[k] * LOG2E;                  // off critical path
            int tt = t + PF + k;
            tt = (tt < Tc) ? tt : (Tc - 1);             // clamp (OOB guard only)
            pre[k] = ep[tt * Cc];                       // refill PF ahead
            float b1 = dpp_shr1(beta, NEGV);
            float b2 = dpp_shr1(b1, NEGV);
            b2 = skip ? b2 : NEGV;
            float m3 = fmaxf(fmaxf(beta, b1), b2);      // v_max3
            float s3 = exp2f(beta - m3) + exp2f(b1 - m3) + exp2f(b2 - m3);
            beta = m3 + __log2f(s3) + e2;
        }
    }
    // tail (< PF iterations), pre[k] holds values for t..t+PF-1
    #pragma unroll
    for (int k = 0; k < PF; ++k) {
        if (t + k < il) {
            float e2 = pre[k] * LOG2E;
            float b1 = dpp_shr1(beta, NEGV);
            float b2 = dpp_shr1(b1, NEGV);
            b2 = skip ? b2 : NEGV;
            float m3 = fmaxf(fmaxf(beta, b1), b2);
            float s3 = exp2f(beta - m3) + exp2f(b1 - m3) + exp2f(b2 - m3);
            beta = m3 + __log2f(s3) + e2;
        }
    }

    // sum of lse over t < il  +  per-sample KL terms (both lane-parallel)
    const float* lrow = lse_arr + (size_t)b * Tc;
    float cl = 0.0f;
    for (int i = lane; i < il; i += 64) cl += lrow[i];
    float kv = (lane < Sc) ? klws[b * Sc + lane] : 0.0f;
    #pragma unroll
    for (int o = 32; o; o >>= 1) {
        cl += __shfl_xor(cl, o);
        kv += __shfl_xor(kv, o);
    }

    const int idx = 2 * tl;
    float last  = __shfl(beta, idx);
    float last2 = __shfl(beta, idx - 1);
    float mx = fmaxf(last, last2);
    float l2 = (mx + __log2f(exp2f(last - mx) + exp2f(last2 - mx))) * LN2;
    float nll = cl - l2;
    if (nll > 1e8f) nll = 0.0f;             // zero_infinity
    float ctc_part = nll / ((float)tl * (float)Bc);

    if (lane == 0) contrib[b] = ctc_part + kv;
}

// Deterministic single-block tree reduction of B floats -> out[0]
__global__ __launch_bounds__(256) void reduce_kernel(
    const float* __restrict__ in, float* __restrict__ out, int n)
{
    __shared__ float sdata[256];
    float s = 0.0f;
    for (int i = threadIdx.x; i < n; i += 256) s += in[i];
    sdata[threadIdx.x] = s;
    __syncthreads();
    for (int off = 128; off; off >>= 1) {
        if ((int)threadIdx.x < off) sdata[threadIdx.x] += sdata[threadIdx.x + off];
        __syncthreads();
    }
    if (threadIdx.x == 0) out[0] = sdata[0];
}

extern "C" void kernel_launch(void* const* d_in, const int* in_sizes, int n_in,
                              void* d_out, int out_size, void* d_ws, size_t ws_size,
                              hipStream_t stream) {
    const float* input  = (const float*)d_in[0];
    const int*   target = (const int*)d_in[1];
    const int*   ilen   = (const int*)d_in[2];
    const int*   tlen   = (const int*)d_in[3];
    const int*   pos    = (const int*)d_in[4];
    const float* ms     = (const float*)d_in[5];
    float* out = (float*)d_out;

    // ws layout: contrib [Bc] | lse [Bc*Tc] | klws [Bc*Sc]  (~3.8 MB)
    float* contrib = (float*)d_ws;
    float* lse     = contrib + Bc;
    float* klws    = lse + (size_t)Bc * Tc;

    lse_kernel<<<(Bc * Tc + 255) / 256, 256, 0, stream>>>(input, lse);
    kl_kernel<<<(Bc * Sc + 255) / 256, 256, 0, stream>>>(input, target, tlen, pos, ms, lse, klws);
    ctc_kernel<<<Bc / 4, 256, 0, stream>>>(input, target, ilen, tlen, lse, klws, contrib);
    reduce_kernel<<<1, 256, 0, stream>>>(contrib, out, Bc);
}